// Round 1
// baseline (403.870 us; speedup 1.0000x reference)
//
#include <hip/hip_runtime.h>

// ---- DPP helpers (row = 16 lanes; our site-group is exactly one DPP row) ----
#define DPP_XOR1        0xB1   // quad_perm [1,0,3,2]
#define DPP_XOR2        0x4E   // quad_perm [2,3,0,1]
#define DPP_HALF_MIRROR 0x141  // lane <-> (l&8)|(7-(l&7))  (flips bit2 at group-of-4 level)
#define DPP_ROW_MIRROR  0x140  // lane <-> 15-l within row  (flips bit3 at group-of-8 level)

template <int CTRL>
__device__ __forceinline__ float dppf(float x) {
    int i = __builtin_bit_cast(int, x);
    int o = __builtin_amdgcn_update_dpp(0, i, CTRL, 0xF, 0xF, true);
    return __builtin_bit_cast(float, o);
}

__device__ __forceinline__ float allmax16(float v) {
    v = fmaxf(v, dppf<DPP_XOR1>(v));
    v = fmaxf(v, dppf<DPP_XOR2>(v));
    v = fmaxf(v, dppf<DPP_HALF_MIRROR>(v));
    v = fmaxf(v, dppf<DPP_ROW_MIRROR>(v));
    return v;
}

__device__ __forceinline__ float allsum16(float v) {
    v += dppf<DPP_XOR1>(v);
    v += dppf<DPP_XOR2>(v);
    v += dppf<DPP_HALF_MIRROR>(v);
    v += dppf<DPP_ROW_MIRROR>(v);
    return v;
}

// One site (b,o,h,w) per 16 lanes. Lane r owns pred row i=r (16 floats in regs).
// I = D = 16.  Sites are contiguous 1KB blocks in pred ([B,O,H,W,I,D] layout).
__global__ __launch_bounds__(256, 6)
void caps_route_kernel(const float* __restrict__ pred,
                       const float* __restrict__ bias,
                       const int* __restrict__ nitp,
                       float* __restrict__ out,
                       int nsites, int bsites) {
    const int tid  = threadIdx.x;
    const int r    = tid & 15;
    const int site = (blockIdx.x << 4) + (tid >> 4);
    if (site >= nsites) return;            // whole 16-lane rows drop out together
    const int nit = nitp[0];

    // Load P[r][0..15] : 4x float4, lane stride 64B, wave covers 4KB contiguous.
    const float4* p4 = reinterpret_cast<const float4*>(pred) + ((size_t)site << 6) + (r << 2);
    float4 q0 = p4[0], q1 = p4[1], q2 = p4[2], q3 = p4[3];
    float P[16] = {q0.x, q0.y, q0.z, q0.w,
                   q1.x, q1.y, q1.z, q1.w,
                   q2.x, q2.y, q2.z, q2.w,
                   q3.x, q3.y, q3.z, q3.w};

    float bi = bias[(size_t)(site % bsites) * 16 + r];   // b[0,o,h,w,r]

    const bool h8 = (r & 8) != 0;
    const bool h4 = (r & 4) != 0;
    const bool h2 = (r & 2) != 0;
    const bool h1 = (r & 1) != 0;

    float o_val = 0.0f;

    // softmax(b) over lanes -> weighted sum (reduce-scatter) -> squash
    auto route_out = [&]() {
        float m = allmax16(bi);
        float e = __expf(bi - m);
        float S = allsum16(e);

        float t[16];
        #pragma unroll
        for (int d = 0; d < 16; ++d) t[d] = e * P[d];

        // reduce-scatter: after 4 stages lane r holds sum_i e_i * P[i][r]
        #pragma unroll
        for (int d = 0; d < 16; ++d) t[d] += dppf<DPP_ROW_MIRROR>(t[d]);
        #pragma unroll
        for (int k = 0; k < 8; ++k) t[k] = h8 ? t[k + 8] : t[k];
        #pragma unroll
        for (int d = 0; d < 8; ++d) t[d] += dppf<DPP_HALF_MIRROR>(t[d]);
        #pragma unroll
        for (int k = 0; k < 4; ++k) t[k] = h4 ? t[k + 4] : t[k];
        #pragma unroll
        for (int d = 0; d < 4; ++d) t[d] += dppf<DPP_XOR2>(t[d]);
        #pragma unroll
        for (int k = 0; k < 2; ++k) t[k] = h2 ? t[k + 2] : t[k];
        #pragma unroll
        for (int d = 0; d < 2; ++d) t[d] += dppf<DPP_XOR1>(t[d]);

        float s_val = (h1 ? t[1] : t[0]) * __builtin_amdgcn_rcpf(S);

        // squash: ||s||^2 across lanes, then lane-local scale
        float nsq = allsum16(s_val * s_val);
        float factor = nsq * __builtin_amdgcn_rsqf(nsq + 1e-7f) *
                       __builtin_amdgcn_rcpf(1.0f + nsq);
        o_val = s_val * factor;   // lane r holds out[r]
    };

    route_out();

    for (int it = 0; it < nit; ++it) {
        // allgather out[0..15] into A[16] on every lane
        float A[16];
        {
            float g = dppf<DPP_XOR1>(o_val);
            A[0] = h1 ? g : o_val;
            A[1] = h1 ? o_val : g;
        }
        {
            float g0 = dppf<DPP_XOR2>(A[0]);
            float g1 = dppf<DPP_XOR2>(A[1]);
            A[2] = h2 ? A[0] : g0;
            A[3] = h2 ? A[1] : g1;
            A[0] = h2 ? g0 : A[0];
            A[1] = h2 ? g1 : A[1];
        }
        {
            float g0 = dppf<DPP_HALF_MIRROR>(A[0]);
            float g1 = dppf<DPP_HALF_MIRROR>(A[1]);
            float g2 = dppf<DPP_HALF_MIRROR>(A[2]);
            float g3 = dppf<DPP_HALF_MIRROR>(A[3]);
            A[4] = h4 ? A[0] : g0;
            A[5] = h4 ? A[1] : g1;
            A[6] = h4 ? A[2] : g2;
            A[7] = h4 ? A[3] : g3;
            A[0] = h4 ? g0 : A[0];
            A[1] = h4 ? g1 : A[1];
            A[2] = h4 ? g2 : A[2];
            A[3] = h4 ? g3 : A[3];
        }
        {
            float g0 = dppf<DPP_ROW_MIRROR>(A[0]);
            float g1 = dppf<DPP_ROW_MIRROR>(A[1]);
            float g2 = dppf<DPP_ROW_MIRROR>(A[2]);
            float g3 = dppf<DPP_ROW_MIRROR>(A[3]);
            float g4 = dppf<DPP_ROW_MIRROR>(A[4]);
            float g5 = dppf<DPP_ROW_MIRROR>(A[5]);
            float g6 = dppf<DPP_ROW_MIRROR>(A[6]);
            float g7 = dppf<DPP_ROW_MIRROR>(A[7]);
            A[8]  = h8 ? A[0] : g0;
            A[9]  = h8 ? A[1] : g1;
            A[10] = h8 ? A[2] : g2;
            A[11] = h8 ? A[3] : g3;
            A[12] = h8 ? A[4] : g4;
            A[13] = h8 ? A[5] : g5;
            A[14] = h8 ? A[6] : g6;
            A[15] = h8 ? A[7] : g7;
            A[0] = h8 ? g0 : A[0];
            A[1] = h8 ? g1 : A[1];
            A[2] = h8 ? g2 : A[2];
            A[3] = h8 ? g3 : A[3];
            A[4] = h8 ? g4 : A[4];
            A[5] = h8 ? g5 : A[5];
            A[6] = h8 ? g6 : A[6];
            A[7] = h8 ? g7 : A[7];
        }

        // agreement: b_r += <P[r,:], out>
        float agr = 0.0f;
        #pragma unroll
        for (int d = 0; d < 16; ++d) agr = fmaf(P[d], A[d], agr);
        bi += agr;

        route_out();
    }

    // out[site*16 + r]; whole wave writes 256B contiguous
    out[((size_t)site << 4) + r] = o_val;
}

extern "C" void kernel_launch(void* const* d_in, const int* in_sizes, int n_in,
                              void* d_out, int out_size, void* d_ws, size_t ws_size,
                              hipStream_t stream) {
    const float* pred = (const float*)d_in[0];
    const float* bias = (const float*)d_in[1];
    const int*   nit  = (const int*)d_in[2];
    float* outp = (float*)d_out;

    const int nsites = in_sizes[0] >> 8;   // B*O*H*W  (each site = I*D = 256 floats)
    const int bsites = in_sizes[1] >> 4;   // O*H*W    (bias sites)

    const int sites_per_block = 16;        // 256 threads, 16 lanes per site
    dim3 block(256);
    dim3 grid((nsites + sites_per_block - 1) / sites_per_block);
    caps_route_kernel<<<grid, block, 0, stream>>>(pred, bias, nit, outp, nsites, bsites);
}

// Round 4
// 403.273 us; speedup vs baseline: 1.0015x; 1.0015x over previous
//
#include <hip/hip_runtime.h>

// ---- DPP helpers (row = 16 lanes; our site-group is exactly one DPP row) ----
#define DPP_XOR1        0xB1   // quad_perm [1,0,3,2]          : lane ^= 1
#define DPP_XOR2        0x4E   // quad_perm [2,3,0,1]          : lane ^= 2
#define DPP_HALF_MIRROR 0x141  // mirror within half-row of 8  : lane ^= 7
#define DPP_ROW_MIRROR  0x140  // mirror within row of 16      : lane ^= 15

template <int CTRL>
__device__ __forceinline__ float dppf(float x) {
    int i = __builtin_bit_cast(int, x);
    int o = __builtin_amdgcn_update_dpp(0, i, CTRL, 0xF, 0xF, true);
    return __builtin_bit_cast(float, o);
}

__device__ __forceinline__ float allsum16(float v) {
    v += dppf<DPP_XOR1>(v);
    v += dppf<DPP_XOR2>(v);
    v += dppf<DPP_HALF_MIRROR>(v);
    v += dppf<DPP_ROW_MIRROR>(v);
    return v;
}

// One site (b,o,h,w) per 16 lanes. Lane r owns pred row i=r (16 floats in regs).
// I = D = 16. Sites are contiguous 1KB blocks in pred ([B,O,H,W,I,D] layout).
__global__ __launch_bounds__(256, 4)
void caps_route_kernel(const float* __restrict__ pred,
                       const float* __restrict__ bias,
                       const int* __restrict__ nitp,
                       float* __restrict__ out,
                       int bsites) {
    const int tid   = threadIdx.x;
    const int r     = tid & 15;
    const int bsite = (blockIdx.x << 4) + (tid >> 4);   // site within one batch image
    if (bsite >= bsites) return;
    const size_t site = (size_t)blockIdx.y * bsites + bsite;
    const int nit = nitp[0];

    // Load P[r][0..15] : 4x float4, lane stride 64B, wave covers 4KB contiguous.
    const float4* p4 = reinterpret_cast<const float4*>(pred) + (site << 6) + (r << 2);
    float4 q0 = p4[0], q1 = p4[1], q2 = p4[2], q3 = p4[3];
    float P[16] = {q0.x, q0.y, q0.z, q0.w,
                   q1.x, q1.y, q1.z, q1.w,
                   q2.x, q2.y, q2.z, q2.w,
                   q3.x, q3.y, q3.z, q3.w};

    float bi = bias[((size_t)bsite << 4) + r];   // b[0,o,h,w,r]

    const bool h8 = (r & 8) != 0;
    const bool h4 = (r & 4) != 0;
    const bool h2 = (r & 2) != 0;
    const bool h1 = (r & 1) != 0;

    float o_val = 0.0f;

    // softmax(b) over 16 lanes -> weighted sum (DPP reduce-scatter) -> squash.
    // No max-subtraction: |b| <= nit * max|<P_i,out>| ~ 12, exp() safe in fp32.
    auto route_out = [&]() {
        float e = __expf(bi);
        float S = allsum16(e);

        float t[16];
        #pragma unroll
        for (int d = 0; d < 16; ++d) t[d] = e * P[d];

        // reduce-scatter: after each butterfly stage, select on the matching
        // lane-bit so lane r ends holding u[r] = sum_i e_i * P[i][r].
        #pragma unroll
        for (int d = 0; d < 16; ++d) t[d] += dppf<DPP_ROW_MIRROR>(t[d]);
        #pragma unroll
        for (int k = 0; k < 8; ++k) t[k] = h8 ? t[k + 8] : t[k];
        #pragma unroll
        for (int d = 0; d < 8; ++d) t[d] += dppf<DPP_HALF_MIRROR>(t[d]);
        #pragma unroll
        for (int k = 0; k < 4; ++k) t[k] = h4 ? t[k + 4] : t[k];
        #pragma unroll
        for (int d = 0; d < 4; ++d) t[d] += dppf<DPP_XOR2>(t[d]);
        #pragma unroll
        for (int k = 0; k < 2; ++k) t[k] = h2 ? t[k + 2] : t[k];   // restored (r2 bug)
        #pragma unroll
        for (int d = 0; d < 2; ++d) t[d] += dppf<DPP_XOR1>(t[d]);
        float u = h1 ? t[1] : t[0];

        // squash on s = u/S, with 1/S folded into the final scale:
        // nsq = (sum u^2)/S^2 ; o = u * (1/S) * nsq/sqrt(nsq+eps)/(1+nsq)
        float rS  = __builtin_amdgcn_rcpf(S);
        float nsq = allsum16(u * u) * rS * rS;
        float k_s = rS * nsq * __builtin_amdgcn_rsqf(nsq + 1e-7f) *
                    __builtin_amdgcn_rcpf(1.0f + nsq);
        o_val = u * k_s;   // lane r holds out[r]
    };

    route_out();

    const int gbase = (tid & 48) << 2;   // 16-lane group base, byte addr for bpermute

    for (int it = 0; it < nit; ++it) {
        // allgather out[0..15] via ds_bpermute (DS pipe, overlaps VALU)
        const int ov = __builtin_bit_cast(int, o_val);
        float agr = 0.0f;
        #pragma unroll
        for (int j = 0; j < 16; ++j) {
            float Aj = __builtin_bit_cast(float,
                        __builtin_amdgcn_ds_bpermute(gbase + (j << 2), ov));
            agr = fmaf(P[j], Aj, agr);   // <P[r,:], out>
        }
        bi += agr;
        route_out();
    }

    // out[site*16 + r]; whole wave writes 256B contiguous
    out[(site << 4) + r] = o_val;
}

extern "C" void kernel_launch(void* const* d_in, const int* in_sizes, int n_in,
                              void* d_out, int out_size, void* d_ws, size_t ws_size,
                              hipStream_t stream) {
    const float* pred = (const float*)d_in[0];
    const float* bias = (const float*)d_in[1];
    const int*   nit  = (const int*)d_in[2];
    float* outp = (float*)d_out;

    const int bsites = in_sizes[1] >> 4;              // O*H*W  (bias sites)
    const int batch  = (int)(((size_t)in_sizes[0] >> 8) / (size_t)bsites);  // B

    dim3 block(256);                                   // 16 sites per block
    dim3 grid((bsites + 15) / 16, batch);
    caps_route_kernel<<<grid, block, 0, stream>>>(pred, bias, nit, outp, bsites);
}